// Round 3
// baseline (7442.741 us; speedup 1.0000x reference)
//
#include <hip/hip_runtime.h>
#include <cstdint>
#include <cstddef>

typedef unsigned short u16;
typedef __attribute__((ext_vector_type(8))) short bf16x8;  // 8 x bf16 (4 VGPRs)
typedef __attribute__((ext_vector_type(4))) float f32x4;

#define DEV __device__ __forceinline__

DEV float bf2f(u16 h) { union { unsigned int u; float f; } x; x.u = ((unsigned int)h) << 16; return x.f; }
DEV u16 f2bf(float f) {
    union { float f; unsigned int u; } x; x.f = f;
    unsigned int u = x.u;
    return (u16)((u + 0x7fffu + ((u >> 16) & 1u)) >> 16);   // RNE
}
DEV float sigf(float x) { return 1.0f / (1.0f + expf(-x)); }
DEV f32x4 mfma16(bf16x8 a, bf16x8 b, f32x4 c) {
    return __builtin_amdgcn_mfma_f32_16x16x32_bf16(a, b, c, 0, 0, 0);
}

// B=256, T=256, E=128, H=128 (per direction), H2=256. ALL tensors fp32.
// Time chunked by CH=64 for the xg buffers.
#define CH 64

// ---------------------------------------------------------------------------
// xg GEMM, first (bi) layer, fp32 in, fp32 out.
// out[tl*256+b, n] = bias[n] + sum_e embed[b,t0+tl,e]*Wih[n,e]
// A (embed) split hi/lo bf16 -> logical K = 256; W single bf16 (duplicated).
// ---------------------------------------------------------------------------
__global__ __launch_bounds__(256) void xg_fr_kernel(
    const float* __restrict__ embed,
    const float* __restrict__ Wf, const float* __restrict__ bf_,
    const float* __restrict__ Wr, const float* __restrict__ br_,
    float* __restrict__ xgf, float* __restrict__ xgr, int t0f, int t0r)
{
    __shared__ __align__(16) u16 As[64][40];
    __shared__ __align__(16) u16 Bs[64][40];
    int tid = threadIdx.x;
    int bx = blockIdx.x;          // 0..7  (N/64)
    int by = blockIdx.y;          // 0..511
    bool isR = by >= 256;
    int m0 = (by & 255) * 64;
    const float* W    = isR ? Wr  : Wf;
    const float* bias = isR ? br_ : bf_;
    float* out        = isR ? xgr : xgf;
    int tbase         = isR ? t0r : t0f;
    int n0 = bx * 64;

    int r  = tid >> 2;            // 0..63 staging row
    int kc = (tid & 3) * 8;       // 0,8,16,24
    int m  = m0 + r;
    int tl = m >> 8, bb = m & 255;
    const float* arow = embed + ((size_t)(bb * 256 + (tbase + tl)) * 128);
    const float* brow = W + ((size_t)(n0 + r) * 128);

    f32x4 acc[4];
    #pragma unroll
    for (int i = 0; i < 4; ++i) acc[i] = (f32x4){0.f, 0.f, 0.f, 0.f};
    int lane = tid & 63, w = tid >> 6;
    int fr_ = lane & 15, kb0 = (lane >> 4) * 8;

    for (int kt = 0; kt < 8; ++kt) {
        int sc = (kt & 3) * 32 + kc;       // source col 0..127
        bool lo = kt >= 4;
        f32x4 va = *(const f32x4*)(arow + sc);
        f32x4 vb = *(const f32x4*)(arow + sc + 4);
        f32x4 wa = *(const f32x4*)(brow + sc);
        f32x4 wb = *(const f32x4*)(brow + sc + 4);
        bf16x8 hv, wv;
        #pragma unroll
        for (int i = 0; i < 8; ++i) {
            float v = (i < 4) ? va[i] : vb[i - 4];
            u16 hi = f2bf(v);
            hv[i] = (short)(lo ? f2bf(v - bf2f(hi)) : hi);
            float wf = (i < 4) ? wa[i] : wb[i - 4];
            wv[i] = (short)f2bf(wf);
        }
        *(bf16x8*)&As[r][kc] = hv;
        *(bf16x8*)&Bs[r][kc] = wv;
        __syncthreads();
        bf16x8 bfrg = *(const bf16x8*)&Bs[w * 16 + fr_][kb0];
        #pragma unroll
        for (int mt = 0; mt < 4; ++mt) {
            bf16x8 afrg = *(const bf16x8*)&As[mt * 16 + fr_][kb0];
            acc[mt] = mfma16(afrg, bfrg, acc[mt]);
        }
        __syncthreads();
    }
    int col = n0 + w * 16 + fr_;
    float bvv = bias[col];
    int rq = (lane >> 4) * 4;
    #pragma unroll
    for (int mt = 0; mt < 4; ++mt)
        #pragma unroll
        for (int rr = 0; rr < 4; ++rr) {
            int mrow = m0 + mt * 16 + rq + rr;
            out[(size_t)mrow * 512 + col] = acc[mt][rr] + bvv;
        }
}

// ---------------------------------------------------------------------------
// xg GEMM, H2 layers, fp32 in/out. X split hi/lo (logical K=512 over 256).
// out[tl*256+b, n] = bias[n] + sum_k X[(t0+tl)*256+b, k] * W[n, k]
// ---------------------------------------------------------------------------
__global__ __launch_bounds__(256) void xg_l_kernel(
    const float* __restrict__ X, const float* __restrict__ W,
    const float* __restrict__ bias, float* __restrict__ out, int t0)
{
    __shared__ __align__(16) u16 As[64][40];
    __shared__ __align__(16) u16 Bs[64][40];
    int tid = threadIdx.x;
    int bx = blockIdx.x;          // 0..15
    int by = blockIdx.y;          // 0..255
    int m0 = by * 64, n0 = bx * 64;
    int r  = tid >> 2;
    int kc = (tid & 3) * 8;
    int m  = m0 + r;
    int tl = m >> 8, bb = m & 255;
    const float* arow = X + ((size_t)((t0 + tl) * 256 + bb) * 256);
    const float* brow = W + ((size_t)(n0 + r) * 256);

    f32x4 acc[4];
    #pragma unroll
    for (int i = 0; i < 4; ++i) acc[i] = (f32x4){0.f, 0.f, 0.f, 0.f};
    int lane = tid & 63, w = tid >> 6;
    int fr_ = lane & 15, kb0 = (lane >> 4) * 8;

    for (int kt = 0; kt < 16; ++kt) {
        int sc = (kt & 7) * 32 + kc;       // source col 0..255
        bool lo = kt >= 8;
        f32x4 va = *(const f32x4*)(arow + sc);
        f32x4 vb = *(const f32x4*)(arow + sc + 4);
        f32x4 wa = *(const f32x4*)(brow + sc);
        f32x4 wb = *(const f32x4*)(brow + sc + 4);
        bf16x8 hv, wv;
        #pragma unroll
        for (int i = 0; i < 8; ++i) {
            float v = (i < 4) ? va[i] : vb[i - 4];
            u16 hi = f2bf(v);
            hv[i] = (short)(lo ? f2bf(v - bf2f(hi)) : hi);
            float wf = (i < 4) ? wa[i] : wb[i - 4];
            wv[i] = (short)f2bf(wf);
        }
        *(bf16x8*)&As[r][kc] = hv;
        *(bf16x8*)&Bs[r][kc] = wv;
        __syncthreads();
        bf16x8 bfrg = *(const bf16x8*)&Bs[w * 16 + fr_][kb0];
        #pragma unroll
        for (int mt = 0; mt < 4; ++mt) {
            bf16x8 afrg = *(const bf16x8*)&As[mt * 16 + fr_][kb0];
            acc[mt] = mfma16(afrg, bfrg, acc[mt]);
        }
        __syncthreads();
    }
    int col = n0 + w * 16 + fr_;
    float bvv = bias[col];
    int rq = (lane >> 4) * 4;
    #pragma unroll
    for (int mt = 0; mt < 4; ++mt)
        #pragma unroll
        for (int rr = 0; rr < 4; ++rr) {
            int mrow = m0 + mt * 16 + rq + rr;
            out[(size_t)mrow * 1024 + col] = acc[mt][rr] + bvv;
        }
}

// ---------------------------------------------------------------------------
// layernorm over 256 channels, one wave per row. RESID adds R first. In-place.
// ---------------------------------------------------------------------------
template<int RESID>
__global__ __launch_bounds__(256) void ln_kernel(
    float* __restrict__ X, const float* __restrict__ R,
    const float* __restrict__ gw, const float* __restrict__ bw)
{
    int row  = blockIdx.x * 4 + (threadIdx.x >> 6);
    int lane = threadIdx.x & 63;
    float* xr = X + (size_t)row * 256;
    f32x4 v = *(const f32x4*)(xr + lane * 4);
    if (RESID) {
        f32x4 u = *(const f32x4*)(R + (size_t)row * 256 + lane * 4);
        v += u;
    }
    float s = v[0] + v[1] + v[2] + v[3];
    #pragma unroll
    for (int mm = 1; mm < 64; mm <<= 1) s += __shfl_xor(s, mm, 64);
    float mu = s * (1.0f / 256.0f);
    f32x4 e = v - mu;
    float q = e[0]*e[0] + e[1]*e[1] + e[2]*e[2] + e[3]*e[3];
    #pragma unroll
    for (int mm = 1; mm < 64; mm <<= 1) q += __shfl_xor(q, mm, 64);
    float rs = rsqrtf(q * (1.0f / 256.0f) + 1e-5f);
    int c0 = lane * 4;
    f32x4 o;
    #pragma unroll
    for (int i = 0; i < 4; ++i) o[i] = e[i] * rs * gw[c0 + i] + bw[c0 + i];
    *(f32x4*)(xr + lane * 4) = o;
}

// ---------------------------------------------------------------------------
// ONE LSTM time-step. No inter-block sync: h/c live in global fp32 buffers,
// ordering guaranteed by stream serialization between step launches.
// Block = 16 samples x 16 h-cols x 4 gates. Grid (H/16, 16, NDIR).
// OUTMODE 0: bi layer -> X1[t][b][dir*128+col]   (dir=1 runs reversed scan)
// OUTMODE 1: H2 layer -> X2[t][b][col]
// OUTMODE 2: H2 layer -> y[b][col] at t==lastidx[b] (bn+relu, fp32 out)
// ---------------------------------------------------------------------------
template<int H, int OUTMODE>
__global__ __launch_bounds__(256) void step_kernel(
    const float* __restrict__ xgf, const float* __restrict__ xgr,
    const float* __restrict__ whhf, const float* __restrict__ whhr,
    const float* __restrict__ hprev, float* __restrict__ hcur,
    float* __restrict__ cbuf,
    float* __restrict__ xout, float* __restrict__ yout,
    const int* __restrict__ lastidx,
    const float* __restrict__ bng, const float* __restrict__ bnb,
    int t, int s0)
{
    __shared__ __align__(16) u16 Wl[64][H + 8];   // 64 gate-rows x K (bf16)
    __shared__ __align__(16) u16 Al[32][H + 8];   // 16 hi + 16 lo sample rows
    __shared__ __align__(16) float Gl[32][68];    // recurrent contributions

    int tid = threadIdx.x;
    int ct = blockIdx.x, sg = blockIdx.y, dir = blockIdx.z;
    const float* xg  = dir ? xgr : xgf;
    const float* whh = dir ? whhr : whhf;
    size_t doff = (size_t)dir * 256 * H;

    // stage Whh slice (fp32 -> bf16): row n = g*16+jj <- Whh[g*H + ct*16+jj, :]
    for (int idx = tid; idx < 64 * (H / 8); idx += 256) {
        int n = idx / (H / 8), kv = (idx % (H / 8)) * 8;
        int g = n >> 4, jj = n & 15;
        const float* src = whh + (size_t)(g * H + ct * 16 + jj) * H + kv;
        f32x4 va = *(const f32x4*)src;
        f32x4 vb = *(const f32x4*)(src + 4);
        bf16x8 wv;
        #pragma unroll
        for (int i = 0; i < 8; ++i) wv[i] = (short)f2bf((i < 4) ? va[i] : vb[i - 4]);
        *(bf16x8*)&Wl[n][kv] = wv;
    }
    // stage h_prev (fp32 -> bf16 hi/lo rows)
    const float* hp = hprev + doff + (size_t)sg * 16 * H;
    for (int idx = tid; idx < 16 * H; idx += 256) {
        int sa = idx / H, k = idx % H;
        float v = (t == 0) ? 0.f : hp[sa * H + k];
        u16 hh = f2bf(v);
        Al[sa][k]      = hh;
        Al[16 + sa][k] = f2bf(v - bf2f(hh));
    }
    __syncthreads();

    int lane = tid & 63, w = tid >> 6;
    int fr_ = lane & 15, kb0 = (lane >> 4) * 8, rq = (lane >> 4) * 4;
    f32x4 acc0 = (f32x4){0.f, 0.f, 0.f, 0.f};
    f32x4 acc1 = (f32x4){0.f, 0.f, 0.f, 0.f};
    #pragma unroll
    for (int kt = 0; kt < H / 32; ++kt) {
        int kb = kt * 32 + kb0;
        bf16x8 b  = *(const bf16x8*)&Wl[w * 16 + fr_][kb];
        bf16x8 a0 = *(const bf16x8*)&Al[fr_][kb];
        bf16x8 a1 = *(const bf16x8*)&Al[16 + fr_][kb];
        acc0 = mfma16(a0, b, acc0);   // hi-part contributions
        acc1 = mfma16(a1, b, acc1);   // lo-part contributions
    }
    #pragma unroll
    for (int rr = 0; rr < 4; ++rr) {
        Gl[rq + rr][w * 16 + fr_]      = acc0[rr];
        Gl[16 + rq + rr][w * 16 + fr_] = acc1[rr];
    }
    __syncthreads();

    int s_loc = tid >> 4, jc = tid & 15;
    int sample = sg * 16 + s_loc;
    int col = ct * 16 + jc;
    int xrow = dir ? (CH - 1 - (t - s0)) : (t - s0);
    const float* xp = xg + (size_t)(xrow * 256 + sample) * (4 * H) + col;
    float g0 = xp[0]     + Gl[s_loc][jc]      + Gl[16 + s_loc][jc];
    float g1 = xp[H]     + Gl[s_loc][16 + jc] + Gl[16 + s_loc][16 + jc];
    float g2 = xp[2 * H] + Gl[s_loc][32 + jc] + Gl[16 + s_loc][32 + jc];
    float g3 = xp[3 * H] + Gl[s_loc][48 + jc] + Gl[16 + s_loc][48 + jc];

    float c = (t == 0) ? 0.f : cbuf[doff + (size_t)sample * H + col];
    c = sigf(g1) * c + sigf(g0) * tanhf(g2);
    float h = sigf(g3) * tanhf(c);
    cbuf[doff + (size_t)sample * H + col] = c;
    hcur[doff + (size_t)sample * H + col] = h;

    if (OUTMODE == 0) {
        int tt = dir ? (255 - t) : t;
        xout[((size_t)tt * 256 + sample) * 256 + dir * 128 + col] = h;
    } else if (OUTMODE == 1) {
        xout[((size_t)t * 256 + sample) * 256 + col] = h;
    } else {
        // robust int64/int32 sniff: int64 -> odd int32 words are all zero
        bool is64 = (lastidx[1] | lastidx[3] | lastidx[5] | lastidx[7] |
                     lastidx[9] | lastidx[11] | lastidx[13] | lastidx[15]) == 0;
        int lastb = is64 ? lastidx[2 * sample] : lastidx[sample];
        if (t == lastb) {
            float y = h * (bng[col] * rsqrtf(1.0f + 1e-5f)) + bnb[col];
            y = y > 0.f ? y : 0.f;
            yout[(size_t)sample * 256 + col] = y;
        }
    }
}

// ---------------------------------------------------------------------------
// Launch
// ---------------------------------------------------------------------------
extern "C" void kernel_launch(void* const* d_in, const int* in_sizes, int n_in,
                              void* d_out, int out_size, void* d_ws, size_t ws_size,
                              hipStream_t stream)
{
    (void)in_sizes; (void)n_in; (void)out_size; (void)ws_size;
    const float* embed = (const float*)d_in[0];
    const int* lastidx = (const int*)d_in[1];
    const float* Wih_f = (const float*)d_in[2];
    const float* Whh_f = (const float*)d_in[3];
    const float* b_f   = (const float*)d_in[4];
    const float* Wih_r = (const float*)d_in[5];
    const float* Whh_r = (const float*)d_in[6];
    const float* b_r   = (const float*)d_in[7];
    const float* ln1g  = (const float*)d_in[8];
    const float* ln1b  = (const float*)d_in[9];
    const float* W1ih  = (const float*)d_in[10];
    const float* W1hh  = (const float*)d_in[11];
    const float* b1    = (const float*)d_in[12];
    const float* ln2g  = (const float*)d_in[13];
    const float* ln2b  = (const float*)d_in[14];
    const float* W2ih  = (const float*)d_in[15];
    const float* W2hh  = (const float*)d_in[16];
    const float* b2    = (const float*)d_in[17];
    const float* bng   = (const float*)d_in[18];
    const float* bnb   = (const float*)d_in[19];

    char* ws = (char*)d_ws;
    float* XG  = (float*)(ws);                               // 64 MiB chunk buf
    float* XGr = XG + (size_t)16384 * 512;                   // (stage 1 rev half)
    float* X1  = (float*)(ws + (size_t)64 * 1024 * 1024);    // 64 MiB
    float* X2  = (float*)(ws + (size_t)128 * 1024 * 1024);   // 64 MiB
    float* hA  = (float*)(ws + (size_t)192 * 1024 * 1024);   // 256 KiB
    float* hB  = hA + 65536;                                 // 256 KiB
    float* cS  = hB + 65536;                                 // 256 KiB

    // stage 1: bidirectional H=128 LSTM -> X1 (raw concat)
    for (int i = 0; i < 4; ++i) {
        xg_fr_kernel<<<dim3(8, 512), 256, 0, stream>>>(
            embed, Wih_f, b_f, Wih_r, b_r, XG, XGr, CH * i, 256 - CH * (i + 1));
        for (int tl = 0; tl < CH; ++tl) {
            int t = CH * i + tl;
            float* hp = (t & 1) ? hB : hA;
            float* hc = (t & 1) ? hA : hB;
            step_kernel<128, 0><<<dim3(8, 16, 2), 256, 0, stream>>>(
                XG, XGr, Whh_f, Whh_r, hp, hc, cS,
                X1, nullptr, nullptr, nullptr, nullptr, t, CH * i);
        }
    }
    ln_kernel<0><<<16384, 256, 0, stream>>>(X1, nullptr, ln1g, ln1b);

    // stage 2: H2 LSTM layer 1 -> X2 (raw)
    for (int i = 0; i < 4; ++i) {
        xg_l_kernel<<<dim3(16, 256), 256, 0, stream>>>(X1, W1ih, b1, XG, CH * i);
        for (int tl = 0; tl < CH; ++tl) {
            int t = CH * i + tl;
            float* hp = (t & 1) ? hB : hA;
            float* hc = (t & 1) ? hA : hB;
            step_kernel<256, 1><<<dim3(16, 16, 1), 256, 0, stream>>>(
                XG, XG, W1hh, W1hh, hp, hc, cS,
                X2, nullptr, nullptr, nullptr, nullptr, t, CH * i);
        }
    }
    ln_kernel<1><<<16384, 256, 0, stream>>>(X2, X1, ln2g, ln2b);

    // stage 3: H2 LSTM layer 2 -> gathered y (fp32 out)
    for (int i = 0; i < 4; ++i) {
        xg_l_kernel<<<dim3(16, 256), 256, 0, stream>>>(X2, W2ih, b2, XG, CH * i);
        for (int tl = 0; tl < CH; ++tl) {
            int t = CH * i + tl;
            float* hp = (t & 1) ? hB : hA;
            float* hc = (t & 1) ? hA : hB;
            step_kernel<256, 2><<<dim3(16, 16, 1), 256, 0, stream>>>(
                XG, XG, W2hh, W2hh, hp, hc, cS,
                nullptr, (float*)d_out, lastidx, bng, bnb, t, CH * i);
        }
    }
}